// Round 2
// baseline (533.706 us; speedup 1.0000x reference)
//
#include <hip/hip_runtime.h>
#include <cmath>

#define N_TOK 8192
#define C_DIM 768
#define H_DIM 3072
#define NEXP  8
#define PADCAP 17408      // 2*N_TOK + NEXP*128
#define MAXMT  136        // PADCAP/128

typedef short short8 __attribute__((ext_vector_type(8)));
typedef float f32x4  __attribute__((ext_vector_type(4)));

// fp32 -> bf16 round-to-nearest-even (finite inputs only)
__device__ __forceinline__ unsigned short f2b(float f) {
  unsigned int u = __float_as_uint(f);
  u += 0x7fffu + ((u >> 16) & 1u);
  return (unsigned short)(u >> 16);
}
__device__ __forceinline__ float b2f(unsigned short u) {
  return __uint_as_float((unsigned int)u << 16);
}
__device__ __forceinline__ void gll(const char* g, char* l) {
  __builtin_amdgcn_global_load_lds((const __attribute__((address_space(1))) void*)g,
                                   (__attribute__((address_space(3))) void*)l, 16, 0, 0);
}

// ---------------- gating: fp64 scores, top-2, softmax, counts ----------------
__global__ __launch_bounds__(256) void gate_kernel(
    const float* __restrict__ x, const float* __restrict__ gw,
    const float* __restrict__ gb, int* __restrict__ counts,
    int* __restrict__ tok_e, int* __restrict__ tok_r, float* __restrict__ tok_w) {
  __shared__ float gwl[NEXP * C_DIM];
  __shared__ double red[256][NEXP];
  int tid = threadIdx.x;
  const float4* gw4 = (const float4*)gw;
  float4* gl4 = (float4*)gwl;
  for (int i = tid; i < NEXP * C_DIM / 4; i += 256) gl4[i] = gw4[i];
  __syncthreads();
  int tl = tid & 63;   // token within block
  int kc = tid >> 6;   // k-chunk 0..3 (192 each)
  int t = blockIdx.x * 64 + tl;
  double acc[NEXP];
#pragma unroll
  for (int e = 0; e < NEXP; e++) acc[e] = 0.0;
  const float* xr = x + (size_t)t * C_DIM;
  for (int k = kc * 192; k < kc * 192 + 192; k++) {
    double xv = (double)xr[k];
#pragma unroll
    for (int e = 0; e < NEXP; e++) acc[e] += xv * (double)gwl[e * C_DIM + k];
  }
#pragma unroll
  for (int e = 0; e < NEXP; e++) red[tid][e] = acc[e];
  __syncthreads();
  if (tid < 64) {
    double s[NEXP];
#pragma unroll
    for (int e = 0; e < NEXP; e++)
      s[e] = (double)gb[e] + red[tid][e] + red[tid + 64][e] + red[tid + 128][e] + red[tid + 192][e];
    // top-2, ties -> lower index first (matches jax.lax.top_k)
    double best = s[0], sec = -1e300; int bi = 0, si = -1;
#pragma unroll
    for (int e = 1; e < NEXP; e++) {
      if (s[e] > best)      { sec = best; si = bi; best = s[e]; bi = e; }
      else if (s[e] > sec)  { sec = s[e]; si = e; }
    }
    double ex = exp(sec - best);
    double den = 1.0 + ex;
    tok_e[2 * t] = bi;  tok_e[2 * t + 1] = si;
    tok_w[2 * t] = (float)(1.0 / den);  tok_w[2 * t + 1] = (float)(ex / den);
    tok_r[2 * t]     = atomicAdd(&counts[bi], 1);
    tok_r[2 * t + 1] = atomicAdd(&counts[si], 1);
  }
}

// ---------------- padded offsets (segments rounded up to 128 rows) ----------
__global__ void offsets_kernel(const int* __restrict__ counts, int* __restrict__ po) {
  if (threadIdx.x == 0 && blockIdx.x == 0) {
    int s = 0;
    for (int e = 0; e < NEXP; e++) { po[e] = s; s += (counts[e] + 127) & ~127; }
    po[NEXP] = s;
  }
}

// -------- scatter token ids + gate weights; record inverse map tok_pos ------
__global__ __launch_bounds__(256) void scatter_kernel(
    const int* __restrict__ tok_e, const int* __restrict__ tok_r,
    const float* __restrict__ tok_w, const int* __restrict__ po,
    int* __restrict__ perm_t, float* __restrict__ perm_w,
    int* __restrict__ tok_pos) {
  int t = blockIdx.x * 256 + threadIdx.x;
#pragma unroll
  for (int k = 0; k < 2; k++) {
    int e = tok_e[2 * t + k];
    int pos = po[e] + tok_r[2 * t + k];
    perm_t[pos] = t;
    perm_w[pos] = tok_w[2 * t + k];
    tok_pos[2 * t + k] = pos;
  }
}

// ---------------- gather x rows into permuted bf16 matrix -------------------
__global__ __launch_bounds__(256) void gather_kernel(
    const float* __restrict__ x, const int* __restrict__ po,
    const int* __restrict__ perm_t, unsigned short* __restrict__ xg) {
  int row = blockIdx.x * 4 + (threadIdx.x >> 6);
  if (row >= po[NEXP]) return;
  int l = threadIdx.x & 63;
  int t = perm_t[row];
  const float4* src = (const float4*)(x + (size_t)t * C_DIM);
  ushort4* dst = (ushort4*)(xg + (size_t)row * C_DIM);
#pragma unroll
  for (int j = 0; j < 3; j++) {
    float4 v = src[l + j * 64];
    ushort4 o; o.x = f2b(v.x); o.y = f2b(v.y); o.z = f2b(v.z); o.w = f2b(v.w);
    dst[l + j * 64] = o;
  }
}

// ---------------- fp32 -> bf16 weight conversion ----------------------------
__global__ __launch_bounds__(256) void wconv_kernel(
    const float* __restrict__ wfc, const float* __restrict__ wproj,
    unsigned short* __restrict__ wfcb, unsigned short* __restrict__ wpjb) {
  const int n4 = NEXP * H_DIM * C_DIM / 4;
  int stride = gridDim.x * blockDim.x;
  for (int i = blockIdx.x * blockDim.x + threadIdx.x; i < 2 * n4; i += stride) {
    const float4* s; ushort4* d; int j;
    if (i < n4) { s = (const float4*)wfc;   d = (ushort4*)wfcb; j = i; }
    else        { s = (const float4*)wproj; d = (ushort4*)wpjb; j = i - n4; }
    float4 v = s[j];
    ushort4 o; o.x = f2b(v.x); o.y = f2b(v.y); o.z = f2b(v.z); o.w = f2b(v.w);
    d[j] = o;
  }
}

// ---------- 512-thread 128x256 tile, BK=64, 3-buffer deep pipeline ----------
// 8 waves in 2x4: wave tile 64x64 -> acc 4x4 f32x4 = 64 regs; ds_read:MFMA
// ratio 16:32 per K-tile (2x better than the old 64x32 wave tile).
// Pipeline: 3 LDS buffers of 48KB (A 16K + B 32K); tile t+2 staged while
// computing tile t; raw s_barrier with COUNTED s_waitcnt vmcnt(6) -> the
// prefetch queue is never drained to 0 inside the loop (the __syncthreads
// vmcnt(0) drain was the old ~30% MfmaUtil ceiling). 2 phases per K-tile
// (s=0/1) with a mid s_barrier + s_setprio(1) around each 16-MFMA cluster.
// LDS rows are 128B = 8 chunks of 16B; chunk c of row r at slot c^((r>>1)&7)
// (measured 0 bank conflicts with this swizzle). gll writes linearly; the
// swizzle is applied by pre-swizzling the GLOBAL source chunk (rule #21).
#define STAGE6(kt, bufbase) do {                                   \
    size_t kb_ = (size_t)(kt) * 128;                               \
    char* nb_ = lds + (bufbase);                                   \
    gll(gA0 + kb_, nb_ + wb);                                      \
    gll(gA1 + kb_, nb_ + 8192 + wb);                               \
    gll(gB0p + kb_, nb_ + 16384 + wb);                             \
    gll(gB1p + kb_, nb_ + 24576 + wb);                             \
    gll(gB2p + kb_, nb_ + 32768 + wb);                             \
    gll(gB3p + kb_, nb_ + 40960 + wb);                             \
  } while (0)

__device__ __forceinline__ void gemm_big(
    const unsigned short* A, int lda, const unsigned short* B, int ldb, int K,
    char* lds, int tid, f32x4 acc[4][4]) {
  const int w = tid >> 6, l = tid & 63;
  const int wr = w >> 2, wc = w & 3;
  const int ra0 = wr * 64 + (l & 15);            // A row base (M)
  const int rb0 = wc * 64 + (l & 15);            // B row base (N)
  const int kc = l >> 4;
  const int sa0 = (kc ^ ((ra0 >> 1) & 7)) * 16;  // swizzled chunk slot (const over mi)
  const int sb0 = (kc ^ ((rb0 >> 1) & 7)) * 16;
  // staging: A = 1024 chunks (128 rows x 8), B = 2048 chunks (256 rows x 8).
  // thread handles A chunks {tid, tid+512}, B chunks {tid+j*512, j=0..3}.
  // LDS dest is linear (cid*16); global src chunk is pre-swizzled.
  const int rA0 = tid >> 3,           cA0 = (tid & 7) ^ ((rA0 >> 1) & 7);
  const int rA1 = (512 + tid) >> 3,   cA1 = ((512 + tid) & 7) ^ ((rA1 >> 1) & 7);
  const int rB0 = tid >> 3,           cB0 = (tid & 7) ^ ((rB0 >> 1) & 7);
  const int rB1 = (512 + tid) >> 3,   cB1 = ((512 + tid) & 7) ^ ((rB1 >> 1) & 7);
  const int rB2 = (1024 + tid) >> 3,  cB2 = ((1024 + tid) & 7) ^ ((rB2 >> 1) & 7);
  const int rB3 = (1536 + tid) >> 3,  cB3 = ((1536 + tid) & 7) ^ ((rB3 >> 1) & 7);
  const char* gA0  = (const char*)(A + (size_t)rA0 * lda) + cA0 * 16;
  const char* gA1  = (const char*)(A + (size_t)rA1 * lda) + cA1 * 16;
  const char* gB0p = (const char*)(B + (size_t)rB0 * ldb) + cB0 * 16;
  const char* gB1p = (const char*)(B + (size_t)rB1 * ldb) + cB1 * 16;
  const char* gB2p = (const char*)(B + (size_t)rB2 * ldb) + cB2 * 16;
  const char* gB3p = (const char*)(B + (size_t)rB3 * ldb) + cB3 * 16;
  const int wb = w * 1024;             // wave-uniform LDS base (+ lane*16 by HW)
  const int iters = K >> 6;            // BK=64
  // prologue: tiles 0,1 -> buffers 0,1 (12 loads in flight)
  STAGE6(0, 0);
  STAGE6(1, 49152);
  int bc = 0, bn2 = 98304;             // buffer of tile kt / tile kt+2
#pragma unroll 1
  for (int kt = 0; kt < iters; kt++) {
    // publish tile kt: my 6 loads for kt are the oldest; vmcnt(6) leaves the
    // 6 loads of kt+1 in flight (never drain to 0 in steady state). Barrier
    // also proves every wave finished reading tile kt-1's buffer.
    if (kt < iters - 1) asm volatile("s_waitcnt vmcnt(6)\n\ts_barrier" ::: "memory");
    else                asm volatile("s_waitcnt vmcnt(0)\n\ts_barrier" ::: "memory");
    if (kt + 2 < iters) STAGE6(kt + 2, bn2);   // overwrites buffer of kt-1
    char* bb = lds + bc;
#pragma unroll
    for (int s = 0; s < 2; s++) {
      const int sxa = sa0 ^ (s << 6);          // chunk ^4 == byte ^64
      const int sxb = sb0 ^ (s << 6);
      short8 af[4], bf[4];
#pragma unroll
      for (int mi = 0; mi < 4; mi++)
        af[mi] = *(const short8*)(bb + (ra0 + mi * 16) * 128 + sxa);
#pragma unroll
      for (int ni = 0; ni < 4; ni++)
        bf[ni] = *(const short8*)(bb + 16384 + (rb0 + ni * 16) * 128 + sxb);
      __builtin_amdgcn_s_setprio(1);
#pragma unroll
      for (int mi = 0; mi < 4; mi++)
#pragma unroll
        for (int ni = 0; ni < 4; ni++)
          acc[mi][ni] = __builtin_amdgcn_mfma_f32_16x16x32_bf16(af[mi], bf[ni], acc[mi][ni], 0, 0, 0);
      __builtin_amdgcn_s_setprio(0);
      if (s == 0) asm volatile("s_barrier" ::: "memory");   // phase split
    }
    bc += 49152;  if (bc == 147456)  bc = 0;
    bn2 += 49152; if (bn2 == 147456) bn2 = 0;
  }
}

// ---------------- FC1: h = gelu(xg @ w_fc^T + b_fc), bf16 out ---------------
// grid 1632 = 8 XCD-slots x 17 strips x 12 col-blocks (bid%8 -> XCD locality)
__global__ __launch_bounds__(512, 2) void fc1_kernel(
    const unsigned short* __restrict__ xg, const unsigned short* __restrict__ wfcb,
    const float* __restrict__ bfc, const int* __restrict__ po,
    unsigned short* __restrict__ h) {
  __shared__ char lds[147456];
  int bid = blockIdx.x;
  int r8 = bid & 7, g8 = bid >> 3;     // g8: 0..203
  int col = g8 % 12;
  int Sp  = g8 / 12;                   // 0..16
  int y   = r8 * 17 + Sp;              // 0..135
  int row0 = y * 128;
  if (row0 >= po[NEXP]) return;
  int e = 0;
#pragma unroll
  for (int i = 1; i < NEXP; i++) if (row0 >= po[i]) e = i;
  int n0 = col * 256;
  int tid = threadIdx.x;
  f32x4 acc[4][4];
#pragma unroll
  for (int mi = 0; mi < 4; mi++)
#pragma unroll
    for (int ni = 0; ni < 4; ni++) acc[mi][ni] = (f32x4){0.f, 0.f, 0.f, 0.f};
  gemm_big(xg + (size_t)row0 * C_DIM, C_DIM,
           wfcb + (size_t)e * H_DIM * C_DIM + (size_t)n0 * C_DIM, C_DIM, C_DIM,
           lds, tid, acc);
  int w = tid >> 6, l = tid & 63;
  int wr = w >> 2, wc = w & 3, q = l >> 4;
  const float* bias = bfc + (size_t)e * H_DIM;
  // gelu(tanh-approx) via sigmoid: 0.5v(1+tanh(z)) = v / (1 + exp2(-2*log2e*z))
#pragma unroll
  for (int ni = 0; ni < 4; ni++) {
    int colw = n0 + wc * 64 + ni * 16 + (l & 15);
    float bv = bias[colw];
#pragma unroll
    for (int mi = 0; mi < 4; mi++) {
#pragma unroll
      for (int r = 0; r < 4; r++) {
        int row = row0 + wr * 64 + mi * 16 + q * 4 + r;
        float v = acc[mi][ni][r] + bv;
        float z = v * fmaf(0.0356774081f, v * v, 0.7978845608f);
        float ex = __builtin_amdgcn_exp2f(-2.8853900818f * z);
        float g = v * __builtin_amdgcn_rcpf(1.0f + ex);
        h[(size_t)row * H_DIM + colw] = f2b(g);
      }
    }
  }
}

// ---------------- FC2: part[z][pos] = w * (h_z @ w_proj^T + b_proj*[z==0]) --
// split-K=2 (K=1536 each), 816 blocks, plain bf16 partial stores (no atomics)
__global__ __launch_bounds__(512, 2) void fc2_kernel(
    const unsigned short* __restrict__ h, const unsigned short* __restrict__ wpjb,
    const float* __restrict__ bproj, const int* __restrict__ po,
    const float* __restrict__ perm_w, unsigned short* __restrict__ part) {
  __shared__ char lds[147456];
  int bid = blockIdx.x;
  int r8 = bid & 7, g8 = bid >> 3;     // g8: 0..101
  int col = g8 % 3;                    // 3 col-blocks of 256
  int qq  = g8 / 3;                    // 0..33
  int z   = qq & 1;                    // k-split 0..1
  int Sp  = qq >> 1;                   // 0..16
  int y   = r8 * 17 + Sp;              // 0..135
  int row0 = y * 128;
  if (row0 >= po[NEXP]) return;
  int e = 0;
#pragma unroll
  for (int i = 1; i < NEXP; i++) if (row0 >= po[i]) e = i;
  int n0 = col * 256;
  int koff = z * (H_DIM / 2);
  int tid = threadIdx.x;
  f32x4 acc[4][4];
#pragma unroll
  for (int mi = 0; mi < 4; mi++)
#pragma unroll
    for (int ni = 0; ni < 4; ni++) acc[mi][ni] = (f32x4){0.f, 0.f, 0.f, 0.f};
  gemm_big(h + (size_t)row0 * H_DIM + koff, H_DIM,
           wpjb + (size_t)e * C_DIM * H_DIM + (size_t)n0 * H_DIM + koff, H_DIM, H_DIM / 2,
           lds, tid, acc);
  int w = tid >> 6, l = tid & 63;
  int wr = w >> 2, wc = w & 3, q = l >> 4;
  const float* bias = bproj + (size_t)e * C_DIM;
  unsigned short* pz = part + (size_t)z * PADCAP * C_DIM;
#pragma unroll
  for (int mi = 0; mi < 4; mi++) {
#pragma unroll
    for (int r = 0; r < 4; r++) {
      int pos = row0 + wr * 64 + mi * 16 + q * 4 + r;
      float wgt = perm_w[pos];   // 0 for pad rows -> stores 0, never read
#pragma unroll
      for (int ni = 0; ni < 4; ni++) {
        int colw = n0 + wc * 64 + ni * 16 + (l & 15);
        float v = acc[mi][ni][r];
        if (z == 0) v += bias[colw];        // bias exactly once across splits
        pz[(size_t)pos * C_DIM + colw] = f2b(v * wgt);
      }
    }
  }
}

// ---------------- combine: out[t] = sum of the token's 4 partial rows -------
__global__ __launch_bounds__(256) void combine_kernel(
    const unsigned short* __restrict__ part, const int* __restrict__ tok_pos,
    float* __restrict__ out) {
  const int NC4 = C_DIM / 4;                       // 192
  int idx = blockIdx.x * 256 + threadIdx.x;        // 0 .. N_TOK*192-1
  int t = idx / NC4, c4 = idx - t * NC4;
  int p0 = tok_pos[2 * t], p1 = tok_pos[2 * t + 1];
  const size_t SP = (size_t)PADCAP * C_DIM;
  const unsigned short* r00 = part + (size_t)p0 * C_DIM + c4 * 4;
  const unsigned short* r10 = part + (size_t)p1 * C_DIM + c4 * 4;
  ushort4 v00 = *(const ushort4*)r00;
  ushort4 v01 = *(const ushort4*)(r00 + SP);
  ushort4 v10 = *(const ushort4*)r10;
  ushort4 v11 = *(const ushort4*)(r10 + SP);
  float4 o;
  o.x = b2f(v00.x) + b2f(v01.x) + b2f(v10.x) + b2f(v11.x);
  o.y = b2f(v00.y) + b2f(v01.y) + b2f(v10.y) + b2f(v11.y);
  o.z = b2f(v00.z) + b2f(v01.z) + b2f(v10.z) + b2f(v11.z);
  o.w = b2f(v00.w) + b2f(v01.w) + b2f(v10.w) + b2f(v11.w);
  ((float4*)out)[idx] = o;
}

extern "C" void kernel_launch(void* const* d_in, const int* in_sizes, int n_in,
                              void* d_out, int out_size, void* d_ws, size_t ws_size,
                              hipStream_t stream) {
  const float* x     = (const float*)d_in[0];
  const float* gw    = (const float*)d_in[1];
  const float* gb    = (const float*)d_in[2];
  const float* wfc   = (const float*)d_in[3];
  const float* bfc   = (const float*)d_in[4];
  const float* wproj = (const float*)d_in[5];
  const float* bproj = (const float*)d_in[6];
  float* out = (float*)d_out;
  char* ws = (char*)d_ws;

  // ws layout (~209.6 MB total; part overlays xg+wfcb which die after FC1)
  int*   counts  = (int*)(ws + 0);
  int*   po      = (int*)(ws + 64);
  int*   tok_e   = (int*)(ws + 256);
  int*   tok_r   = (int*)(ws + 65792);
  float* tok_w   = (float*)(ws + 131328);
  int*   tok_pos = (int*)(ws + 196864);
  int*   perm_t  = (int*)(ws + 262400);
  float* perm_w  = (float*)(ws + 332032);
  const size_t ROUT_END = 401920;
  unsigned short* wpjb = (unsigned short*)(ws + 401920);        // 8x768x3072 bf16 -> ends 38,150,656
  unsigned short* hbuf = (unsigned short*)(ws + 38150656);      // 17408x3072 bf16 -> ends 145,105,408
  unsigned short* xg   = (unsigned short*)(ws + 145105408);     // 17408x768 bf16  -> ends 171,844,096
  unsigned short* wfcb = (unsigned short*)(ws + 171844096);     // 8x3072x768 bf16 -> ends 209,592,832
  unsigned short* part = (unsigned short*)(ws + 145105408);     // 2x17408x768 bf16 (overlay, ends 198,582,784)

  hipMemsetAsync(ws, 0, ROUT_END, stream);

  gate_kernel<<<N_TOK / 64, 256, 0, stream>>>(x, gw, gb, counts, tok_e, tok_r, tok_w);
  offsets_kernel<<<1, 64, 0, stream>>>(counts, po);
  scatter_kernel<<<N_TOK / 256, 256, 0, stream>>>(tok_e, tok_r, tok_w, po, perm_t, perm_w, tok_pos);
  gather_kernel<<<PADCAP / 4, 256, 0, stream>>>(x, po, perm_t, xg);
  wconv_kernel<<<2048, 256, 0, stream>>>(wfc, wproj, wfcb, wpjb);
  fc1_kernel<<<8 * 17 * 12, 512, 0, stream>>>(xg, wfcb, bfc, po, hbuf);
  fc2_kernel<<<8 * 17 * 3 * 2, 512, 0, stream>>>(hbuf, wpjb, bproj, po, perm_w, part);
  combine_kernel<<<N_TOK * (C_DIM / 4) / 256, 256, 0, stream>>>(part, tok_pos, out);
}

// Round 3
// 505.709 us; speedup vs baseline: 1.0554x; 1.0554x over previous
//
#include <hip/hip_runtime.h>
#include <cmath>

#define N_TOK 8192
#define C_DIM 768
#define H_DIM 3072
#define NEXP  8
#define PADCAP 18432      // 2*N_TOK + NEXP*256 (expert segments padded to 256)

typedef short short8 __attribute__((ext_vector_type(8)));
typedef float f32x4  __attribute__((ext_vector_type(4)));

// fp32 -> bf16 round-to-nearest-even (finite inputs only)
__device__ __forceinline__ unsigned short f2b(float f) {
  unsigned int u = __float_as_uint(f);
  u += 0x7fffu + ((u >> 16) & 1u);
  return (unsigned short)(u >> 16);
}
__device__ __forceinline__ float b2f(unsigned short u) {
  return __uint_as_float((unsigned int)u << 16);
}
__device__ __forceinline__ void gll(const char* g, char* l) {
  __builtin_amdgcn_global_load_lds((const __attribute__((address_space(1))) void*)g,
                                   (__attribute__((address_space(3))) void*)l, 16, 0, 0);
}

// ---------------- gating: fp64 scores, top-2, softmax, counts ----------------
__global__ __launch_bounds__(256) void gate_kernel(
    const float* __restrict__ x, const float* __restrict__ gw,
    const float* __restrict__ gb, int* __restrict__ counts,
    int* __restrict__ tok_e, int* __restrict__ tok_r, float* __restrict__ tok_w) {
  __shared__ float gwl[NEXP * C_DIM];
  __shared__ double red[256][NEXP];
  int tid = threadIdx.x;
  const float4* gw4 = (const float4*)gw;
  float4* gl4 = (float4*)gwl;
  for (int i = tid; i < NEXP * C_DIM / 4; i += 256) gl4[i] = gw4[i];
  __syncthreads();
  int tl = tid & 63;   // token within block
  int kc = tid >> 6;   // k-chunk 0..3 (192 each)
  int t = blockIdx.x * 64 + tl;
  double acc[NEXP];
#pragma unroll
  for (int e = 0; e < NEXP; e++) acc[e] = 0.0;
  const float* xr = x + (size_t)t * C_DIM;
  for (int k = kc * 192; k < kc * 192 + 192; k++) {
    double xv = (double)xr[k];
#pragma unroll
    for (int e = 0; e < NEXP; e++) acc[e] += xv * (double)gwl[e * C_DIM + k];
  }
#pragma unroll
  for (int e = 0; e < NEXP; e++) red[tid][e] = acc[e];
  __syncthreads();
  if (tid < 64) {
    double s[NEXP];
#pragma unroll
    for (int e = 0; e < NEXP; e++)
      s[e] = (double)gb[e] + red[tid][e] + red[tid + 64][e] + red[tid + 128][e] + red[tid + 192][e];
    // top-2, ties -> lower index first (matches jax.lax.top_k)
    double best = s[0], sec = -1e300; int bi = 0, si = -1;
#pragma unroll
    for (int e = 1; e < NEXP; e++) {
      if (s[e] > best)      { sec = best; si = bi; best = s[e]; bi = e; }
      else if (s[e] > sec)  { sec = s[e]; si = e; }
    }
    double ex = exp(sec - best);
    double den = 1.0 + ex;
    tok_e[2 * t] = bi;  tok_e[2 * t + 1] = si;
    tok_w[2 * t] = (float)(1.0 / den);  tok_w[2 * t + 1] = (float)(ex / den);
    tok_r[2 * t]     = atomicAdd(&counts[bi], 1);
    tok_r[2 * t + 1] = atomicAdd(&counts[si], 1);
  }
}

// ---------------- padded offsets (segments rounded up to 256 rows) ----------
__global__ void offsets_kernel(const int* __restrict__ counts, int* __restrict__ po) {
  if (threadIdx.x == 0 && blockIdx.x == 0) {
    int s = 0;
    for (int e = 0; e < NEXP; e++) { po[e] = s; s += (counts[e] + 255) & ~255; }
    po[NEXP] = s;
  }
}

// -------- scatter token ids + gate weights; record inverse map tok_pos ------
__global__ __launch_bounds__(256) void scatter_kernel(
    const int* __restrict__ tok_e, const int* __restrict__ tok_r,
    const float* __restrict__ tok_w, const int* __restrict__ po,
    int* __restrict__ perm_t, float* __restrict__ perm_w,
    int* __restrict__ tok_pos) {
  int t = blockIdx.x * 256 + threadIdx.x;
#pragma unroll
  for (int k = 0; k < 2; k++) {
    int e = tok_e[2 * t + k];
    int pos = po[e] + tok_r[2 * t + k];
    perm_t[pos] = t;
    perm_w[pos] = tok_w[2 * t + k];
    tok_pos[2 * t + k] = pos;
  }
}

// ---------------- gather x rows into permuted bf16 matrix -------------------
__global__ __launch_bounds__(256) void gather_kernel(
    const float* __restrict__ x, const int* __restrict__ po,
    const int* __restrict__ perm_t, unsigned short* __restrict__ xg) {
  int row = blockIdx.x * 4 + (threadIdx.x >> 6);
  if (row >= po[NEXP]) return;
  int l = threadIdx.x & 63;
  int t = perm_t[row];           // pad rows: perm_t zeroed -> t=0 (safe, wgt=0)
  const float4* src = (const float4*)(x + (size_t)t * C_DIM);
  ushort4* dst = (ushort4*)(xg + (size_t)row * C_DIM);
#pragma unroll
  for (int j = 0; j < 3; j++) {
    float4 v = src[l + j * 64];
    ushort4 o; o.x = f2b(v.x); o.y = f2b(v.y); o.z = f2b(v.z); o.w = f2b(v.w);
    dst[l + j * 64] = o;
  }
}

// ---------------- fp32 -> bf16 weight conversion (one matrix set) -----------
__global__ __launch_bounds__(256) void wconv_kernel(
    const float* __restrict__ src, unsigned short* __restrict__ dst, int n4) {
  int stride = gridDim.x * blockDim.x;
  for (int i = blockIdx.x * blockDim.x + threadIdx.x; i < n4; i += stride) {
    float4 v = ((const float4*)src)[i];
    ushort4 o; o.x = f2b(v.x); o.y = f2b(v.y); o.z = f2b(v.z); o.w = f2b(v.w);
    ((ushort4*)dst)[i] = o;
  }
}

// ================= 256x256 tile, BK=64, 8-phase deep pipeline ===============
// 512 thr = 8 waves (2M x 4N), wave tile 128x64, acc 8x4 f32x4 (128 regs).
// LDS 128KB = 2 bufs x (A 32K + B 32K); each tile staged as 4 half-tiles
// (A-lo/A-hi/B-lo/B-hi, 16KB = 2 gll/thread each).
// Per iteration: 8 phases over 2 K-tiles (even->buf0, odd->buf1). Phase =
// {ds_read quadrant frags | stage 1 half-tile | barrier | 16 MFMA(setprio) |
// barrier}. Staging schedule (derived from region-free times):
//   p0: A-lo(2i+1)  p1: A-hi(2i+1)  p2: B-lo(2i+2)  p3: B-hi(2i+2)
//   p4: A-lo(2i+2)  p5: A-hi(2i+2)  p6: B-lo(2i+3)  p7: B-hi(2i+3)
// Waits: vmcnt(4) at end of p3 (publishes buf1) and end of p7 (publishes
// buf0) -- FIFO-verified: each retires exactly the 4 half-tiles of the tile
// about to be read, leaving 2 half-tiles (4 loads) in flight. Last iteration
// skips p2..p7 stagings -> its p3 wait must be vmcnt(0).
// Swizzle (verified 0 bank conflicts r1/r2): row = 128B = 8 chunks of 16B;
// chunk q of row r lives at slot q ^ ((r>>1)&7); gll dest linear, global
// source pre-swizzled (rule #21: same involution both sides).
__device__ __forceinline__ void gemm8p(
    const char* __restrict__ Ab, size_t ldaB,
    const char* __restrict__ Bb, size_t ldbB, int ktiles,
    char* lds, int tid, f32x4 acc[8][4]) {
  const int w = tid >> 6, l = tid & 63;
  const int wr = w >> 2, wc = w & 3;
  const int lr = l & 15, kc = l >> 4;
  const int sw = (lr >> 1) & 7;
  const int s0 = ((kc ^ sw) << 4);         // kk=0 slot byte
  const int s1 = s0 ^ 64;                  // kk=1: chunk+4 == slot^4
  const int arow = ((wr << 7) + lr) << 7;            // A: row*128
  const int brow = 32768 + (((wc << 6) + lr) << 7);  // B region
  // staging: thread handles chunks {tid, tid+512} of each 1024-chunk half
  const int rl0 = tid >> 3;
  const int cg0 = (tid & 7) ^ ((rl0 >> 1) & 7);
  const size_t oA0 = (size_t)rl0 * ldaB + (cg0 << 4);
  const size_t oA1 = oA0 + (ldaB << 6);
  const size_t oB0 = (size_t)rl0 * ldbB + (cg0 << 4);
  const size_t oB1 = oB0 + (ldbB << 6);
  const int wb = w << 10;                  // wave-uniform LDS base (+lane*16)

#define SA(b, h, kt) do { \
    const char* s_ = Ab + (size_t)(h) * 128 * ldaB + (size_t)(kt) * 128; \
    gll(s_ + oA0, lds + (b) * 65536 + (h) * 16384 + wb); \
    gll(s_ + oA1, lds + (b) * 65536 + (h) * 16384 + 8192 + wb); } while (0)
#define SB(b, h, kt) do { \
    const char* s_ = Bb + (size_t)(h) * 128 * ldbB + (size_t)(kt) * 128; \
    gll(s_ + oB0, lds + (b) * 65536 + 32768 + (h) * 16384 + wb); \
    gll(s_ + oB1, lds + (b) * 65536 + 32768 + (h) * 16384 + 8192 + wb); } while (0)
#define BAR() asm volatile("s_barrier" ::: "memory")
#define RDA(B, mb) do { \
    for (int mi = 0; mi < 4; mi++) { \
      af[mi][0] = *(const short8*)(lds + (B) + arow + ((mb) + mi) * 2048 + s0); \
      af[mi][1] = *(const short8*)(lds + (B) + arow + ((mb) + mi) * 2048 + s1); } } while (0)
#define RDB(B, nb) do { \
    for (int ni = 0; ni < 2; ni++) { \
      bf[(nb) + ni][0] = *(const short8*)(lds + (B) + brow + ((nb) + ni) * 2048 + s0); \
      bf[(nb) + ni][1] = *(const short8*)(lds + (B) + brow + ((nb) + ni) * 2048 + s1); } } while (0)
#define MM(mb, nb) do { \
    __builtin_amdgcn_s_setprio(1); \
    for (int mi = 0; mi < 4; mi++) \
      for (int ni = 0; ni < 2; ni++) \
        for (int kk = 0; kk < 2; kk++) \
          acc[(mb) + mi][(nb) + ni] = __builtin_amdgcn_mfma_f32_16x16x32_bf16( \
              af[mi][kk], bf[(nb) + ni][kk], acc[(mb) + mi][(nb) + ni], 0, 0, 0); \
    __builtin_amdgcn_s_setprio(0); } while (0)

  short8 af[4][2], bf[4][2];
  // prologue: tile0 (4 halves) then B of tile1 -> first wait retires tile0
  SB(0, 0, 0); SB(0, 1, 0); SA(0, 0, 0); SA(0, 1, 0);
  SB(1, 0, 1); SB(1, 1, 1);
  asm volatile("s_waitcnt vmcnt(4)" ::: "memory");
  BAR();
  const int iters = ktiles >> 1;
#pragma unroll 1
  for (int i = 0; i < iters; i++) {
    const int t1 = 2 * i + 1, t2 = 2 * i + 2, t3 = 2 * i + 3;
    const bool nl = (i + 1 < iters);
    // ---- K-tile 2i from buf0 ----
    RDA(0, 0); RDB(0, 0);          // p0
    SA(1, 0, t1);
    BAR(); MM(0, 0); BAR();
    RDB(0, 2);                     // p1
    SA(1, 1, t1);
    BAR(); MM(0, 2); BAR();
    RDA(0, 4);                     // p2
    if (nl) SB(0, 0, t2);
    BAR(); MM(4, 2); BAR();
    if (nl) SB(0, 1, t2);          // p3
    BAR(); MM(4, 0);
    if (nl) asm volatile("s_waitcnt vmcnt(4)" ::: "memory");
    else    asm volatile("s_waitcnt vmcnt(0)" ::: "memory");
    BAR();                         // publishes buf1 (tile 2i+1)
    // ---- K-tile 2i+1 from buf1 ----
    RDA(65536, 0); RDB(65536, 0);  // p4
    if (nl) SA(0, 0, t2);
    BAR(); MM(0, 0); BAR();
    RDB(65536, 2);                 // p5
    if (nl) SA(0, 1, t2);
    BAR(); MM(0, 2); BAR();
    RDA(65536, 4);                 // p6
    if (nl) SB(1, 0, t3);
    BAR(); MM(4, 2); BAR();
    if (nl) SB(1, 1, t3);          // p7
    BAR(); MM(4, 0);
    if (nl) {
      asm volatile("s_waitcnt vmcnt(4)" ::: "memory");
      BAR();                       // publishes buf0 (tile 2i+2)
    }
  }
#undef SA
#undef SB
#undef BAR
#undef RDA
#undef RDB
#undef MM
}

// ---------------- FC1: h = gelu(xg @ w_fc^T + b_fc), bf16 out ---------------
// grid 864 = 8 XCD-slots x 9 strips x 12 col-blocks
__global__ __launch_bounds__(512, 2) void fc1_kernel(
    const unsigned short* __restrict__ xg, const unsigned short* __restrict__ wfcb,
    const float* __restrict__ bfc, const int* __restrict__ po,
    unsigned short* __restrict__ h) {
  __shared__ char lds[131072];
  int bid = blockIdx.x;
  int r8 = bid & 7, g8 = bid >> 3;     // g8: 0..107
  int col = g8 % 12;
  int Sp  = g8 / 12;                   // 0..8
  int y   = r8 * 9 + Sp;               // 0..71
  int row0 = y * 256;
  if (row0 >= po[NEXP]) return;
  int e = 0;
#pragma unroll
  for (int i = 1; i < NEXP; i++) if (row0 >= po[i]) e = i;
  int n0 = col * 256;
  int tid = threadIdx.x;
  f32x4 acc[8][4];
#pragma unroll
  for (int mi = 0; mi < 8; mi++)
#pragma unroll
    for (int ni = 0; ni < 4; ni++) acc[mi][ni] = (f32x4){0.f, 0.f, 0.f, 0.f};
  gemm8p((const char*)(xg + (size_t)row0 * C_DIM), (size_t)C_DIM * 2,
         (const char*)(wfcb + (size_t)e * H_DIM * C_DIM + (size_t)n0 * C_DIM),
         (size_t)C_DIM * 2, C_DIM / 64, lds, tid, acc);
  int w = tid >> 6, l = tid & 63;
  int wr = w >> 2, wc = w & 3, lr = l & 15, q = l >> 4;
  const float* bias = bfc + (size_t)e * H_DIM;
  // gelu(tanh-approx) via sigmoid: 0.5v(1+tanh(z)) = v / (1 + exp2(-2*log2e*z))
#pragma unroll
  for (int ni = 0; ni < 4; ni++) {
    int colw = n0 + wc * 64 + ni * 16 + lr;
    float bv = bias[colw];
#pragma unroll
    for (int mi = 0; mi < 8; mi++) {
#pragma unroll
      for (int r = 0; r < 4; r++) {
        int row = row0 + wr * 128 + mi * 16 + q * 4 + r;
        float v = acc[mi][ni][r] + bv;
        float z = v * fmaf(0.0356774081f, v * v, 0.7978845608f);
        float ex = __builtin_amdgcn_exp2f(-2.8853900818f * z);
        float g = v * __builtin_amdgcn_rcpf(1.0f + ex);
        h[(size_t)row * H_DIM + colw] = f2b(g);
      }
    }
  }
}

// ---------------- FC2: part[pos] = w * (h @ w_proj^T + b_proj) --------------
// K=3072 single pass, grid 216 = 8 x 9 x 3 (one full CU round)
__global__ __launch_bounds__(512, 2) void fc2_kernel(
    const unsigned short* __restrict__ h, const unsigned short* __restrict__ wpjb,
    const float* __restrict__ bproj, const int* __restrict__ po,
    const float* __restrict__ perm_w, unsigned short* __restrict__ part) {
  __shared__ char lds[131072];
  int bid = blockIdx.x;
  int r8 = bid & 7, g8 = bid >> 3;     // g8: 0..26
  int col = g8 % 3;
  int Sp  = g8 / 3;                    // 0..8
  int y   = r8 * 9 + Sp;               // 0..71
  int row0 = y * 256;
  if (row0 >= po[NEXP]) return;
  int e = 0;
#pragma unroll
  for (int i = 1; i < NEXP; i++) if (row0 >= po[i]) e = i;
  int n0 = col * 256;
  int tid = threadIdx.x;
  f32x4 acc[8][4];
#pragma unroll
  for (int mi = 0; mi < 8; mi++)
#pragma unroll
    for (int ni = 0; ni < 4; ni++) acc[mi][ni] = (f32x4){0.f, 0.f, 0.f, 0.f};
  gemm8p((const char*)(h + (size_t)row0 * H_DIM), (size_t)H_DIM * 2,
         (const char*)(wpjb + (size_t)e * C_DIM * H_DIM + (size_t)n0 * H_DIM),
         (size_t)H_DIM * 2, H_DIM / 64, lds, tid, acc);
  int w = tid >> 6, l = tid & 63;
  int wr = w >> 2, wc = w & 3, lr = l & 15, q = l >> 4;
  const float* bias = bproj + (size_t)e * C_DIM;
#pragma unroll
  for (int mi = 0; mi < 8; mi++) {
#pragma unroll
    for (int r = 0; r < 4; r++) {
      int pos = row0 + wr * 128 + mi * 16 + q * 4 + r;
      float wgt = perm_w[pos];   // 0 for pad rows -> stores 0, never read
#pragma unroll
      for (int ni = 0; ni < 4; ni++) {
        int colw = n0 + wc * 64 + ni * 16 + lr;
        float v = acc[mi][ni][r] + bias[colw];
        part[(size_t)pos * C_DIM + colw] = f2b(v * wgt);
      }
    }
  }
}

// ---------------- combine: out[t] = part[p0] + part[p1] ---------------------
__global__ __launch_bounds__(256) void combine_kernel(
    const unsigned short* __restrict__ part, const int* __restrict__ tok_pos,
    float* __restrict__ out) {
  const int NC4 = C_DIM / 4;                       // 192
  int idx = blockIdx.x * 256 + threadIdx.x;        // 0 .. N_TOK*192-1
  int t = idx / NC4, c4 = idx - t * NC4;
  int p0 = tok_pos[2 * t], p1 = tok_pos[2 * t + 1];
  ushort4 v0 = *(const ushort4*)(part + (size_t)p0 * C_DIM + c4 * 4);
  ushort4 v1 = *(const ushort4*)(part + (size_t)p1 * C_DIM + c4 * 4);
  float4 o;
  o.x = b2f(v0.x) + b2f(v1.x);
  o.y = b2f(v0.y) + b2f(v1.y);
  o.z = b2f(v0.z) + b2f(v1.z);
  o.w = b2f(v0.w) + b2f(v1.w);
  ((float4*)out)[idx] = o;
}

extern "C" void kernel_launch(void* const* d_in, const int* in_sizes, int n_in,
                              void* d_out, int out_size, void* d_ws, size_t ws_size,
                              hipStream_t stream) {
  const float* x     = (const float*)d_in[0];
  const float* gw    = (const float*)d_in[1];
  const float* gb    = (const float*)d_in[2];
  const float* wfc   = (const float*)d_in[3];
  const float* bfc   = (const float*)d_in[4];
  const float* wproj = (const float*)d_in[5];
  const float* bproj = (const float*)d_in[6];
  float* out = (float*)d_out;
  char* ws = (char*)d_ws;

  // ws layout (~179.7 MB): wpjb overlays wfcb (dead after fc1); part overlays
  // xg (dead after fc1). wpjb conversion runs AFTER fc1 for the overlay.
  int*   counts  = (int*)(ws + 0);
  int*   po      = (int*)(ws + 64);
  int*   tok_e   = (int*)(ws + 256);
  int*   tok_r   = (int*)(ws + 65792);
  float* tok_w   = (float*)(ws + 131328);
  int*   tok_pos = (int*)(ws + 196864);
  int*   perm_t  = (int*)(ws + 262400);      // 18432 ints -> 336128
  float* perm_w  = (float*)(ws + 336128);    // 18432 f32  -> 409856
  const size_t ROUT_END = 409856;
  unsigned short* wfcb = (unsigned short*)(ws + 409856);     // 8x3072x768 bf16 -> 38,158,592
  unsigned short* wpjb = (unsigned short*)(ws + 409856);     // overlay after fc1
  unsigned short* xg   = (unsigned short*)(ws + 38158592);   // 18432x768 bf16 -> 66,470,144
  unsigned short* part = (unsigned short*)(ws + 38158592);   // overlay after fc1
  unsigned short* hbuf = (unsigned short*)(ws + 66470144);   // 18432x3072 bf16 -> 179,716,352

  hipMemsetAsync(ws, 0, ROUT_END, stream);

  const int WN4 = NEXP * H_DIM * C_DIM / 4;
  gate_kernel<<<N_TOK / 64, 256, 0, stream>>>(x, gw, gb, counts, tok_e, tok_r, tok_w);
  offsets_kernel<<<1, 64, 0, stream>>>(counts, po);
  scatter_kernel<<<N_TOK / 256, 256, 0, stream>>>(tok_e, tok_r, tok_w, po, perm_t, perm_w, tok_pos);
  gather_kernel<<<PADCAP / 4, 256, 0, stream>>>(x, po, perm_t, xg);
  wconv_kernel<<<2048, 256, 0, stream>>>(wfc, wfcb, WN4);
  fc1_kernel<<<8 * 9 * 12, 512, 0, stream>>>(xg, wfcb, bfc, po, hbuf);
  wconv_kernel<<<2048, 256, 0, stream>>>(wproj, wpjb, WN4);
  fc2_kernel<<<8 * 9 * 3, 512, 0, stream>>>(hbuf, wpjb, bproj, po, perm_w, part);
  combine_kernel<<<N_TOK * (C_DIM / 4) / 256, 256, 0, stream>>>(part, tok_pos, out);
}

// Round 4
// 498.429 us; speedup vs baseline: 1.0708x; 1.0146x over previous
//
#include <hip/hip_runtime.h>
#include <cmath>

#define N_TOK 8192
#define C_DIM 768
#define H_DIM 3072
#define NEXP  8
#define PADCAP 18432      // 2*N_TOK + NEXP*256 (expert segments padded to 256)

typedef short short8 __attribute__((ext_vector_type(8)));
typedef unsigned short ushort8 __attribute__((ext_vector_type(8)));
typedef float f32x4  __attribute__((ext_vector_type(4)));

// fp32 -> bf16 round-to-nearest-even (finite inputs only)
__device__ __forceinline__ unsigned short f2b(float f) {
  unsigned int u = __float_as_uint(f);
  u += 0x7fffu + ((u >> 16) & 1u);
  return (unsigned short)(u >> 16);
}
__device__ __forceinline__ float b2f(unsigned short u) {
  return __uint_as_float((unsigned int)u << 16);
}
__device__ __forceinline__ void gll(const char* g, char* l) {
  __builtin_amdgcn_global_load_lds((const __attribute__((address_space(1))) void*)g,
                                   (__attribute__((address_space(3))) void*)l, 16, 0, 0);
}

// ---------------- gating: fp64 scores, top-2, softmax, counts ----------------
__global__ __launch_bounds__(256) void gate_kernel(
    const float* __restrict__ x, const float* __restrict__ gw,
    const float* __restrict__ gb, int* __restrict__ counts,
    int* __restrict__ tok_e, int* __restrict__ tok_r, float* __restrict__ tok_w) {
  __shared__ float gwl[NEXP * C_DIM];
  __shared__ double red[256][NEXP];
  int tid = threadIdx.x;
  const float4* gw4 = (const float4*)gw;
  float4* gl4 = (float4*)gwl;
  for (int i = tid; i < NEXP * C_DIM / 4; i += 256) gl4[i] = gw4[i];
  __syncthreads();
  int tl = tid & 63;   // token within block
  int kc = tid >> 6;   // k-chunk 0..3 (192 each)
  int t = blockIdx.x * 64 + tl;
  double acc[NEXP];
#pragma unroll
  for (int e = 0; e < NEXP; e++) acc[e] = 0.0;
  const float* xr = x + (size_t)t * C_DIM;
  for (int k = kc * 192; k < kc * 192 + 192; k++) {
    double xv = (double)xr[k];
#pragma unroll
    for (int e = 0; e < NEXP; e++) acc[e] += xv * (double)gwl[e * C_DIM + k];
  }
#pragma unroll
  for (int e = 0; e < NEXP; e++) red[tid][e] = acc[e];
  __syncthreads();
  if (tid < 64) {
    double s[NEXP];
#pragma unroll
    for (int e = 0; e < NEXP; e++)
      s[e] = (double)gb[e] + red[tid][e] + red[tid + 64][e] + red[tid + 128][e] + red[tid + 192][e];
    // top-2, ties -> lower index first (matches jax.lax.top_k)
    double best = s[0], sec = -1e300; int bi = 0, si = -1;
#pragma unroll
    for (int e = 1; e < NEXP; e++) {
      if (s[e] > best)      { sec = best; si = bi; best = s[e]; bi = e; }
      else if (s[e] > sec)  { sec = s[e]; si = e; }
    }
    double ex = exp(sec - best);
    double den = 1.0 + ex;
    tok_e[2 * t] = bi;  tok_e[2 * t + 1] = si;
    tok_w[2 * t] = (float)(1.0 / den);  tok_w[2 * t + 1] = (float)(ex / den);
    tok_r[2 * t]     = atomicAdd(&counts[bi], 1);
    tok_r[2 * t + 1] = atomicAdd(&counts[si], 1);
  }
}

// ---------------- padded offsets (segments rounded up to 256 rows) ----------
__global__ void offsets_kernel(const int* __restrict__ counts, int* __restrict__ po) {
  if (threadIdx.x == 0 && blockIdx.x == 0) {
    int s = 0;
    for (int e = 0; e < NEXP; e++) { po[e] = s; s += (counts[e] + 255) & ~255; }
    po[NEXP] = s;
  }
}

// -------- scatter token ids + gate weights; record inverse map tok_pos ------
__global__ __launch_bounds__(256) void scatter_kernel(
    const int* __restrict__ tok_e, const int* __restrict__ tok_r,
    const float* __restrict__ tok_w, const int* __restrict__ po,
    int* __restrict__ perm_t, float* __restrict__ perm_w,
    int* __restrict__ tok_pos) {
  int t = blockIdx.x * 256 + threadIdx.x;
#pragma unroll
  for (int k = 0; k < 2; k++) {
    int e = tok_e[2 * t + k];
    int pos = po[e] + tok_r[2 * t + k];
    perm_t[pos] = t;
    perm_w[pos] = tok_w[2 * t + k];
    tok_pos[2 * t + k] = pos;
  }
}

// ---------------- gather x rows into permuted bf16 matrix -------------------
__global__ __launch_bounds__(256) void gather_kernel(
    const float* __restrict__ x, const int* __restrict__ po,
    const int* __restrict__ perm_t, unsigned short* __restrict__ xg) {
  int row = blockIdx.x * 4 + (threadIdx.x >> 6);
  if (row >= po[NEXP]) return;
  int l = threadIdx.x & 63;
  int t = perm_t[row];           // pad rows: perm_t zeroed -> t=0 (safe, wgt=0)
  const float4* src = (const float4*)(x + (size_t)t * C_DIM);
  ushort4* dst = (ushort4*)(xg + (size_t)row * C_DIM);
#pragma unroll
  for (int j = 0; j < 3; j++) {
    float4 v = src[l + j * 64];
    ushort4 o; o.x = f2b(v.x); o.y = f2b(v.y); o.z = f2b(v.z); o.w = f2b(v.w);
    dst[l + j * 64] = o;
  }
}

// ---------------- fp32 -> bf16 weight conversion (one matrix set) -----------
__global__ __launch_bounds__(256) void wconv_kernel(
    const float* __restrict__ src, unsigned short* __restrict__ dst, int n4) {
  int stride = gridDim.x * blockDim.x;
  for (int i = blockIdx.x * blockDim.x + threadIdx.x; i < n4; i += stride) {
    float4 v = ((const float4*)src)[i];
    ushort4 o; o.x = f2b(v.x); o.y = f2b(v.y); o.z = f2b(v.z); o.w = f2b(v.w);
    ((ushort4*)dst)[i] = o;
  }
}

// ---------- 512-thread 128x128 tile, BK=64, LDS double-buffer (FC1) ---------
// r1-proven structure: 2 blocks/CU so co-resident blocks fill barrier
// bubbles -- tolerates fc1's short K (768 = 12 K-tiles) where the deep
// 8-phase pipeline cannot amortize its fill/drain.
__device__ __forceinline__ void gemm_core512(
    const unsigned short* A, int lda, const unsigned short* B, int ldb, int K,
    char* lds, int tid, f32x4 acc[4][2]) {
  const int w = tid >> 6, l = tid & 63;
  const int wr = w >> 2, wc = w & 3;
  const int rowa = wr * 64 + (l & 15);
  const int rowb = wc * 32 + (l & 15);
  const int kc = l >> 4;
  const int sa0 = (kc ^ ((rowa >> 1) & 7)) * 16;
  const int sb0 = (kc ^ ((rowb >> 1) & 7)) * 16;
  const int r0 = tid >> 3,          cg0 = (tid & 7) ^ ((r0 >> 1) & 7);
  const int r1 = (512 + tid) >> 3,  cg1 = ((512 + tid) & 7) ^ ((r1 >> 1) & 7);
  const char* gA0 = (const char*)(A + (size_t)r0 * lda) + cg0 * 16;
  const char* gA1 = (const char*)(A + (size_t)r1 * lda) + cg1 * 16;
  const char* gB0 = (const char*)(B + (size_t)r0 * ldb) + cg0 * 16;
  const char* gB1 = (const char*)(B + (size_t)r1 * ldb) + cg1 * 16;
  const int wb = w * 1024;           // wave-uniform LDS base (+ lane*16 by HW)
  const int iters = K >> 6;
  gll(gA0, lds + wb);
  gll(gA1, lds + 8192 + wb);
  gll(gB0, lds + 16384 + wb);
  gll(gB1, lds + 24576 + wb);
#pragma unroll 1
  for (int kt = 0; kt < iters; kt++) {
    __syncthreads();                       // publishes buf kt&1
    if (kt + 1 < iters) {                  // prefetch tile kt+1 -> other buf
      size_t kb = (size_t)(kt + 1) * 128;  // 64 elems * 2B
      char* nb = lds + ((kt + 1) & 1) * 32768;
      gll(gA0 + kb, nb + wb);
      gll(gA1 + kb, nb + 8192 + wb);
      gll(gB0 + kb, nb + 16384 + wb);
      gll(gB1 + kb, nb + 24576 + wb);
    }
    char* bb = lds + (kt & 1) * 32768;
#pragma unroll
    for (int s = 0; s < 2; s++) {
      const int sxa = sa0 ^ (s << 6);      // chunk index ^4 == byte ^64
      const int sxb = sb0 ^ (s << 6);
      short8 af[4], bf2[2];
#pragma unroll
      for (int mi = 0; mi < 4; mi++)
        af[mi] = *(const short8*)(bb + (rowa + mi * 16) * 128 + sxa);
#pragma unroll
      for (int ni = 0; ni < 2; ni++)
        bf2[ni] = *(const short8*)(bb + 16384 + (rowb + ni * 16) * 128 + sxb);
#pragma unroll
      for (int mi = 0; mi < 4; mi++)
#pragma unroll
        for (int ni = 0; ni < 2; ni++)
          acc[mi][ni] = __builtin_amdgcn_mfma_f32_16x16x32_bf16(af[mi], bf2[ni], acc[mi][ni], 0, 0, 0);
    }
  }
}

// ---------------- FC1: h = gelu(xg @ w_fc^T + b_fc), bf16 out ---------------
// grid 3456 = 8 XCD-slots x 18 strips x 24 col-blocks; 2 blocks/CU -> 96%
// packing over 7 rounds. Epilogue stages the 128x128 bf16 tile through LDS
// (stride 136 ushorts kills write-side bank conflicts to 2-way=free) so
// global stores are contiguous 256B/row -> fixes the 1.74x HBM write
// amplification measured in r3 (WRITE_SIZE 196 MB vs 113 ideal).
__global__ __launch_bounds__(512, 4) void fc1_kernel(
    const unsigned short* __restrict__ xg, const unsigned short* __restrict__ wfcb,
    const float* __restrict__ bfc, const int* __restrict__ po,
    unsigned short* __restrict__ h) {
  __shared__ char lds[65536];
  int bid = blockIdx.x;
  int r8 = bid & 7, g8 = bid >> 3;     // g8: 0..431
  int col = g8 % 24;
  int Sp  = g8 / 24;                   // 0..17
  int y   = r8 * 18 + Sp;              // 0..143
  int row0 = y * 128;
  if (row0 >= po[NEXP]) return;
  int e = 0;
#pragma unroll
  for (int i = 1; i < NEXP; i++) if (row0 >= po[i]) e = i;
  int n0 = col * 128;
  int tid = threadIdx.x;
  f32x4 acc[4][2];
#pragma unroll
  for (int mi = 0; mi < 4; mi++)
#pragma unroll
    for (int ni = 0; ni < 2; ni++) acc[mi][ni] = (f32x4){0.f, 0.f, 0.f, 0.f};
  gemm_core512(xg + (size_t)row0 * C_DIM, C_DIM,
               wfcb + (size_t)e * H_DIM * C_DIM + (size_t)n0 * C_DIM, C_DIM, C_DIM,
               lds, tid, acc);
  int w = tid >> 6, l = tid & 63;
  int wr = w >> 2, wc = w & 3, q = l >> 4, lr = l & 15;
  const float* bias = bfc + (size_t)e * H_DIM;
  // gelu(tanh-approx) via sigmoid: 0.5v(1+tanh(z)) = v / (1 + exp2(-2*log2e*z))
  __syncthreads();                       // all waves done reading gemm LDS
  unsigned short* lout = (unsigned short*)lds;
  const int LST = 136;                   // row stride (ushorts)
#pragma unroll
  for (int ni = 0; ni < 2; ni++) {
    int lcol = wc * 32 + ni * 16 + lr;
    float bv = bias[n0 + lcol];
#pragma unroll
    for (int mi = 0; mi < 4; mi++) {
#pragma unroll
      for (int r = 0; r < 4; r++) {
        int lrow = wr * 64 + mi * 16 + q * 4 + r;
        float v = acc[mi][ni][r] + bv;
        float z = v * fmaf(0.0356774081f, v * v, 0.7978845608f);
        float ex = __builtin_amdgcn_exp2f(-2.8853900818f * z);
        float g = v * __builtin_amdgcn_rcpf(1.0f + ex);
        lout[lrow * LST + lcol] = f2b(g);
      }
    }
  }
  __syncthreads();
  // coalesced write-out: 2048 ushort8 chunks; wave covers 4 full 256B rows
#pragma unroll
  for (int p = 0; p < 4; p++) {
    int idx = p * 512 + tid;
    int row = idx >> 4, c8 = idx & 15;
    ushort8 v = *(const ushort8*)(lout + row * LST + c8 * 8);
    *(ushort8*)(h + (size_t)(row0 + row) * H_DIM + n0 + c8 * 8) = v;
  }
}

// ================= 256x256 tile, BK=64, 8-phase deep pipeline (FC2) =========
// Kept from r3: with K=3072 (24 iterations) and grid 216 (single CU round)
// this is where the counted-vmcnt schedule pays (fc2 dropped out of the
// top-5; inferred ~65-75 us from the flat total with fc1 +40).
__device__ __forceinline__ void gemm8p(
    const char* __restrict__ Ab, size_t ldaB,
    const char* __restrict__ Bb, size_t ldbB, int ktiles,
    char* lds, int tid, f32x4 acc[8][4]) {
  const int w = tid >> 6, l = tid & 63;
  const int wr = w >> 2, wc = w & 3;
  const int lr = l & 15, kc = l >> 4;
  const int sw = (lr >> 1) & 7;
  const int s0 = ((kc ^ sw) << 4);         // kk=0 slot byte
  const int s1 = s0 ^ 64;                  // kk=1: chunk+4 == slot^4
  const int arow = ((wr << 7) + lr) << 7;            // A: row*128
  const int brow = 32768 + (((wc << 6) + lr) << 7);  // B region
  const int rl0 = tid >> 3;
  const int cg0 = (tid & 7) ^ ((rl0 >> 1) & 7);
  const size_t oA0 = (size_t)rl0 * ldaB + (cg0 << 4);
  const size_t oA1 = oA0 + (ldaB << 6);
  const size_t oB0 = (size_t)rl0 * ldbB + (cg0 << 4);
  const size_t oB1 = oB0 + (ldbB << 6);
  const int wb = w << 10;                  // wave-uniform LDS base (+lane*16)

#define SA(b, h, kt) do { \
    const char* s_ = Ab + (size_t)(h) * 128 * ldaB + (size_t)(kt) * 128; \
    gll(s_ + oA0, lds + (b) * 65536 + (h) * 16384 + wb); \
    gll(s_ + oA1, lds + (b) * 65536 + (h) * 16384 + 8192 + wb); } while (0)
#define SB(b, h, kt) do { \
    const char* s_ = Bb + (size_t)(h) * 128 * ldbB + (size_t)(kt) * 128; \
    gll(s_ + oB0, lds + (b) * 65536 + 32768 + (h) * 16384 + wb); \
    gll(s_ + oB1, lds + (b) * 65536 + 32768 + (h) * 16384 + 8192 + wb); } while (0)
#define BAR() asm volatile("s_barrier" ::: "memory")
#define RDA(B, mb) do { \
    for (int mi = 0; mi < 4; mi++) { \
      af[mi][0] = *(const short8*)(lds + (B) + arow + ((mb) + mi) * 2048 + s0); \
      af[mi][1] = *(const short8*)(lds + (B) + arow + ((mb) + mi) * 2048 + s1); } } while (0)
#define RDB(B, nb) do { \
    for (int ni = 0; ni < 2; ni++) { \
      bf[(nb) + ni][0] = *(const short8*)(lds + (B) + brow + ((nb) + ni) * 2048 + s0); \
      bf[(nb) + ni][1] = *(const short8*)(lds + (B) + brow + ((nb) + ni) * 2048 + s1); } } while (0)
#define MM(mb, nb) do { \
    __builtin_amdgcn_s_setprio(1); \
    for (int mi = 0; mi < 4; mi++) \
      for (int ni = 0; ni < 2; ni++) \
        for (int kk = 0; kk < 2; kk++) \
          acc[(mb) + mi][(nb) + ni] = __builtin_amdgcn_mfma_f32_16x16x32_bf16( \
              af[mi][kk], bf[(nb) + ni][kk], acc[(mb) + mi][(nb) + ni], 0, 0, 0); \
    __builtin_amdgcn_s_setprio(0); } while (0)

  short8 af[4][2], bf[4][2];
  // prologue: tile0 (4 halves) then B of tile1 -> first wait retires tile0
  SB(0, 0, 0); SB(0, 1, 0); SA(0, 0, 0); SA(0, 1, 0);
  SB(1, 0, 1); SB(1, 1, 1);
  asm volatile("s_waitcnt vmcnt(4)" ::: "memory");
  BAR();
  const int iters = ktiles >> 1;
#pragma unroll 1
  for (int i = 0; i < iters; i++) {
    const int t1 = 2 * i + 1, t2 = 2 * i + 2, t3 = 2 * i + 3;
    const bool nl = (i + 1 < iters);
    // ---- K-tile 2i from buf0 ----
    RDA(0, 0); RDB(0, 0);          // p0
    SA(1, 0, t1);
    BAR(); MM(0, 0); BAR();
    RDB(0, 2);                     // p1
    SA(1, 1, t1);
    BAR(); MM(0, 2); BAR();
    RDA(0, 4);                     // p2
    if (nl) SB(0, 0, t2);
    BAR(); MM(4, 2); BAR();
    if (nl) SB(0, 1, t2);          // p3
    BAR(); MM(4, 0);
    if (nl) asm volatile("s_waitcnt vmcnt(4)" ::: "memory");
    else    asm volatile("s_waitcnt vmcnt(0)" ::: "memory");
    BAR();                         // publishes buf1 (tile 2i+1)
    // ---- K-tile 2i+1 from buf1 ----
    RDA(65536, 0); RDB(65536, 0);  // p4
    if (nl) SA(0, 0, t2);
    BAR(); MM(0, 0); BAR();
    RDB(65536, 2);                 // p5
    if (nl) SA(0, 1, t2);
    BAR(); MM(0, 2); BAR();
    RDA(65536, 4);                 // p6
    if (nl) SB(1, 0, t3);
    BAR(); MM(4, 2); BAR();
    if (nl) SB(1, 1, t3);          // p7
    BAR(); MM(4, 0);
    if (nl) {
      asm volatile("s_waitcnt vmcnt(4)" ::: "memory");
      BAR();                       // publishes buf0 (tile 2i+2)
    }
  }
#undef SA
#undef SB
#undef BAR
#undef RDA
#undef RDB
#undef MM
}

// ---------------- FC2: part[pos] = w * (h @ w_proj^T + b_proj) --------------
// K=3072 single pass, grid 216 = 8 x 9 x 3 (one full CU round)
__global__ __launch_bounds__(512, 2) void fc2_kernel(
    const unsigned short* __restrict__ h, const unsigned short* __restrict__ wpjb,
    const float* __restrict__ bproj, const int* __restrict__ po,
    const float* __restrict__ perm_w, unsigned short* __restrict__ part) {
  __shared__ char lds[131072];
  int bid = blockIdx.x;
  int r8 = bid & 7, g8 = bid >> 3;     // g8: 0..26
  int col = g8 % 3;
  int Sp  = g8 / 3;                    // 0..8
  int y   = r8 * 9 + Sp;               // 0..71
  int row0 = y * 256;
  if (row0 >= po[NEXP]) return;
  int e = 0;
#pragma unroll
  for (int i = 1; i < NEXP; i++) if (row0 >= po[i]) e = i;
  int n0 = col * 256;
  int tid = threadIdx.x;
  f32x4 acc[8][4];
#pragma unroll
  for (int mi = 0; mi < 8; mi++)
#pragma unroll
    for (int ni = 0; ni < 4; ni++) acc[mi][ni] = (f32x4){0.f, 0.f, 0.f, 0.f};
  gemm8p((const char*)(h + (size_t)row0 * H_DIM), (size_t)H_DIM * 2,
         (const char*)(wpjb + (size_t)e * C_DIM * H_DIM + (size_t)n0 * H_DIM),
         (size_t)H_DIM * 2, H_DIM / 64, lds, tid, acc);
  int w = tid >> 6, l = tid & 63;
  int wr = w >> 2, wc = w & 3, lr = l & 15, q = l >> 4;
  const float* bias = bproj + (size_t)e * C_DIM;
#pragma unroll
  for (int mi = 0; mi < 8; mi++) {
#pragma unroll
    for (int r = 0; r < 4; r++) {
      int pos = row0 + wr * 128 + mi * 16 + q * 4 + r;
      float wgt = perm_w[pos];   // 0 for pad rows -> stores 0, never read
#pragma unroll
      for (int ni = 0; ni < 4; ni++) {
        int colw = n0 + wc * 64 + ni * 16 + lr;
        float v = acc[mi][ni][r] + bias[colw];
        part[(size_t)pos * C_DIM + colw] = f2b(v * wgt);
      }
    }
  }
}

// ---------------- combine: out[t] = part[p0] + part[p1] ---------------------
__global__ __launch_bounds__(256) void combine_kernel(
    const unsigned short* __restrict__ part, const int* __restrict__ tok_pos,
    float* __restrict__ out) {
  const int NC4 = C_DIM / 4;                       // 192
  int idx = blockIdx.x * 256 + threadIdx.x;        // 0 .. N_TOK*192-1
  int t = idx / NC4, c4 = idx - t * NC4;
  int p0 = tok_pos[2 * t], p1 = tok_pos[2 * t + 1];
  ushort4 v0 = *(const ushort4*)(part + (size_t)p0 * C_DIM + c4 * 4);
  ushort4 v1 = *(const ushort4*)(part + (size_t)p1 * C_DIM + c4 * 4);
  float4 o;
  o.x = b2f(v0.x) + b2f(v1.x);
  o.y = b2f(v0.y) + b2f(v1.y);
  o.z = b2f(v0.z) + b2f(v1.z);
  o.w = b2f(v0.w) + b2f(v1.w);
  ((float4*)out)[idx] = o;
}

extern "C" void kernel_launch(void* const* d_in, const int* in_sizes, int n_in,
                              void* d_out, int out_size, void* d_ws, size_t ws_size,
                              hipStream_t stream) {
  const float* x     = (const float*)d_in[0];
  const float* gw    = (const float*)d_in[1];
  const float* gb    = (const float*)d_in[2];
  const float* wfc   = (const float*)d_in[3];
  const float* bfc   = (const float*)d_in[4];
  const float* wproj = (const float*)d_in[5];
  const float* bproj = (const float*)d_in[6];
  float* out = (float*)d_out;
  char* ws = (char*)d_ws;

  // ws layout (~179.7 MB): wpjb overlays wfcb (dead after fc1); part overlays
  // xg (dead after fc1). wpjb conversion runs AFTER fc1 for the overlay.
  int*   counts  = (int*)(ws + 0);
  int*   po      = (int*)(ws + 64);
  int*   tok_e   = (int*)(ws + 256);
  int*   tok_r   = (int*)(ws + 65792);
  float* tok_w   = (float*)(ws + 131328);
  int*   tok_pos = (int*)(ws + 196864);
  int*   perm_t  = (int*)(ws + 262400);      // 18432 ints -> 336128
  float* perm_w  = (float*)(ws + 336128);    // 18432 f32  -> 409856
  const size_t ROUT_END = 409856;
  unsigned short* wfcb = (unsigned short*)(ws + 409856);     // 8x3072x768 bf16 -> 38,158,592
  unsigned short* wpjb = (unsigned short*)(ws + 409856);     // overlay after fc1
  unsigned short* xg   = (unsigned short*)(ws + 38158592);   // 18432x768 bf16 -> 66,470,144
  unsigned short* part = (unsigned short*)(ws + 38158592);   // overlay after fc1
  unsigned short* hbuf = (unsigned short*)(ws + 66470144);   // 18432x3072 bf16 -> 179,716,352

  hipMemsetAsync(ws, 0, ROUT_END, stream);

  const int WN4 = NEXP * H_DIM * C_DIM / 4;
  gate_kernel<<<N_TOK / 64, 256, 0, stream>>>(x, gw, gb, counts, tok_e, tok_r, tok_w);
  offsets_kernel<<<1, 64, 0, stream>>>(counts, po);
  scatter_kernel<<<N_TOK / 256, 256, 0, stream>>>(tok_e, tok_r, tok_w, po, perm_t, perm_w, tok_pos);
  gather_kernel<<<PADCAP / 4, 256, 0, stream>>>(x, po, perm_t, xg);
  wconv_kernel<<<2048, 256, 0, stream>>>(wfc, wfcb, WN4);
  fc1_kernel<<<8 * 18 * 24, 512, 0, stream>>>(xg, wfcb, bfc, po, hbuf);
  wconv_kernel<<<2048, 256, 0, stream>>>(wproj, wpjb, WN4);
  fc2_kernel<<<8 * 9 * 3, 512, 0, stream>>>(hbuf, wpjb, bproj, po, perm_w, part);
  combine_kernel<<<N_TOK * (C_DIM / 4) / 256, 256, 0, stream>>>(part, tok_pos, out);
}